// Round 3
// baseline (20017.607 us; speedup 1.0000x reference)
//
#include <hip/hip_runtime.h>

// ---------------------------------------------------------------------------
// Adaptive-attention LSTM decoder (B=128, P=49, D=E=A=512, V=10000, T=50).
//  * Persistent scan kernel: 64 co-resident blocks, 4 phases/step, fence-free
//    grid barriers (relaxed agent atomics + vmcnt drain). Inter-phase data via
//    agent-scope (sc0 sc1) atomic loads/stores; weights stay L2-cached.
//  * GEMM A-operands bulk-staged to LDS (swizzled) to hide LLC latency.
//  * Gate-interleaved weight packing so LSTM cell updates are thread-local.
//  * Precompute: P1/Ps (input-side gates), visual_att; final: big fc GEMM.
// ---------------------------------------------------------------------------

typedef unsigned short u16;
typedef unsigned long long ull;
typedef short bf16x8 __attribute__((ext_vector_type(8)));
typedef float f32x4 __attribute__((ext_vector_type(4)));

#define MFMA16(a, b, c) __builtin_amdgcn_mfma_f32_16x16x32_bf16(a, b, c, 0, 0, 0)
#define NBLK 64

__device__ __forceinline__ u16 f2bf(float f) {
    union { float f; unsigned u; } v; v.f = f;
    return (u16)((v.u + 0x7fffu + ((v.u >> 16) & 1u)) >> 16);
}
__device__ __forceinline__ float bf2f(u16 h) {
    union { unsigned u; float f; } v; v.u = ((unsigned)h) << 16; return v.f;
}
__device__ __forceinline__ float sigm(float x) {
    x = fminf(fmaxf(x, -30.f), 30.f);
    return 1.f / (1.f + __expf(-x));
}
__device__ __forceinline__ float tanh_(float x) {
    x = fminf(fmaxf(x, -15.f), 15.f);
    float e = __expf(2.f * x);
    return (e - 1.f) / (e + 1.f);
}

// ---- agent-scope (cross-XCD coherent, cache-bypassing) accessors ----
__device__ __forceinline__ ull ldq(const u16* p) {
    return __hip_atomic_load((const ull*)p, __ATOMIC_RELAXED, __HIP_MEMORY_SCOPE_AGENT);
}
__device__ __forceinline__ float ld32(const float* p) {
    return __hip_atomic_load(p, __ATOMIC_RELAXED, __HIP_MEMORY_SCOPE_AGENT);
}
__device__ __forceinline__ unsigned ld32u(const u16* p) {
    return __hip_atomic_load((const unsigned*)p, __ATOMIC_RELAXED, __HIP_MEMORY_SCOPE_AGENT);
}
__device__ __forceinline__ void st32(float* p, float v) {
    __hip_atomic_store(p, v, __ATOMIC_RELAXED, __HIP_MEMORY_SCOPE_AGENT);
}
__device__ __forceinline__ void st32u(u16* p, unsigned v) {
    __hip_atomic_store((unsigned*)p, v, __ATOMIC_RELAXED, __HIP_MEMORY_SCOPE_AGENT);
}
__device__ __forceinline__ void st16(u16* p, u16 v) {
    asm volatile("global_store_short %0, %1, off sc0 sc1" :: "v"(p), "v"((unsigned)v) : "memory");
}

// Fence-free grid barrier: drain own device-scope stores, count arrivals.
__device__ __forceinline__ void grid_barrier(int* bar, int idx) {
    asm volatile("s_waitcnt vmcnt(0)" ::: "memory");
    __syncthreads();
    if (threadIdx.x == 0) {
        __hip_atomic_fetch_add(&bar[idx], 1, __ATOMIC_RELAXED, __HIP_MEMORY_SCOPE_AGENT);
        while (__hip_atomic_load(&bar[idx], __ATOMIC_RELAXED, __HIP_MEMORY_SCOPE_AGENT) < NBLK)
            __builtin_amdgcn_s_sleep(2);
    }
    __syncthreads();
    asm volatile("" ::: "memory");
}

// ---- LDS A-staging: 32 rows x K bf16, XOR-swizzled 16B chunks ----
template<int K>
__device__ __forceinline__ void stageA(u16* lds, const u16* A0, const u16* A1, int asplit,
                                       int lda0, int lda1, int r0) {
    constexpr int K8 = K / 8;
    constexpr int CH = (32 * K8) / 256;
    ull t0[CH], t1[CH];
#pragma unroll
    for (int j = 0; j < CH; ++j) {
        int c = j * 256 + (int)threadIdx.x;
        int row = c / K8, cc = c - row * K8;
        int col = cc * 8;
        const u16* src = (col < asplit) ? (A0 + (size_t)(r0 + row) * lda0 + col)
                                        : (A1 + (size_t)(r0 + row) * lda1 + (col - asplit));
        t0[j] = ldq(src);
        t1[j] = ldq(src + 4);
    }
    __builtin_amdgcn_sched_barrier(0);
#pragma unroll
    for (int j = 0; j < CH; ++j) {
        int c = j * 256 + (int)threadIdx.x;
        int row = c / K8, cc = c - row * K8;
        int sw = cc ^ (row & 7);
        ull* dst = (ull*)(lds + ((row * K8 + sw) << 3));
        dst[0] = t0[j];
        dst[1] = t1[j];
    }
    __syncthreads();
}

template<int K>
__device__ __forceinline__ bf16x8 ldsA(const u16* lds, int row, int kk) {
    constexpr int K8 = K / 8;
    int cc = kk >> 3;
    int sw = cc ^ (row & 7);
    return *(const bf16x8*)(lds + ((row * K8 + sw) << 3));
}

// Wave computes 2 m-tiles x NT n-tiles; A (32 rows x K) from swizzled LDS,
// W row-major [N][K] normal cached loads.
template<int NT, int K>
__device__ __forceinline__ void gemm_lds(const u16* lds, const u16* __restrict__ W,
                                         int n_base, f32x4 acc[2][NT]) {
    const int lane = threadIdx.x & 63, r = lane & 15, lg = lane >> 4;
    for (int k0 = 0; k0 < K; k0 += 32) {
        int kk = k0 + lg * 8;
        bf16x8 a0 = ldsA<K>(lds, r, kk);
        bf16x8 a1 = ldsA<K>(lds, 16 + r, kk);
#pragma unroll
        for (int j = 0; j < NT; ++j) {
            bf16x8 wf = *(const bf16x8*)(W + (size_t)(n_base + j * 16 + r) * K + kk);
            acc[0][j] = MFMA16(a0, wf, acc[0][j]);
            acc[1][j] = MFMA16(a1, wf, acc[1][j]);
        }
    }
}

// Plain-global-A gemm (pre/post kernels only).
__device__ __forceinline__ void gemm_2x4(const u16* __restrict__ A0, const u16* __restrict__ A1,
                                         int asplit, int lda0, int lda1,
                                         const u16* __restrict__ W, int ldw, int K,
                                         int m_base, int n_base, int nt, f32x4 acc[2][4]) {
    const int lane = threadIdx.x & 63, r = lane & 15, lg = lane >> 4;
    for (int k0 = 0; k0 < K; k0 += 32) {
        int kk = k0 + lg * 8;
        const u16* Ab; int ka, lda;
        if (k0 < asplit) { Ab = A0; ka = kk; lda = lda0; }
        else             { Ab = A1; ka = kk - asplit; lda = lda1; }
        bf16x8 a0 = *(const bf16x8*)(Ab + (size_t)(m_base + r) * lda + ka);
        bf16x8 a1 = *(const bf16x8*)(Ab + (size_t)(m_base + 16 + r) * lda + ka);
#pragma unroll
        for (int j = 0; j < 4; ++j) {
            if (j < nt) {
                bf16x8 wf = *(const bf16x8*)(W + (size_t)(n_base + j * 16 + r) * ldw + kk);
                acc[0][j] = MFMA16(a0, wf, acc[0][j]);
                acc[1][j] = MFMA16(a1, wf, acc[1][j]);
            }
        }
    }
}

// ---------------- one-time conversion / packing kernels ----------------

__global__ __launch_bounds__(256) void k_cvt8(
    const float* __restrict__ s0, const float* __restrict__ s1, const float* __restrict__ s2,
    const float* __restrict__ s3, const float* __restrict__ s4, const float* __restrict__ s5,
    const float* __restrict__ s6, const float* __restrict__ s7,
    u16* __restrict__ d0, u16* __restrict__ d1, u16* __restrict__ d2, u16* __restrict__ d3,
    u16* __restrict__ d4, u16* __restrict__ d5, u16* __restrict__ d6, u16* __restrict__ d7) {
    int i = blockIdx.x * 256 + threadIdx.x;
    const int S = 262144;
    if (i < 6 * S) {
        int seg = i >> 18, off = i & (S - 1);
        const float* s = seg == 0 ? s0 : seg == 1 ? s1 : seg == 2 ? s2 : seg == 3 ? s3 : seg == 4 ? s4 : s5;
        u16* d = seg == 0 ? d0 : seg == 1 ? d1 : seg == 2 ? d2 : seg == 3 ? d3 : seg == 4 ? d4 : d5;
        d[off] = f2bf(s[off]);
    } else if (i < 6 * S + 5120000) {
        int off = i - 6 * S;
        d6[off] = f2bf(s6[off]);
    } else {
        int off = i - 6 * S - 5120000;
        if (off < 3211264) d7[off] = f2bf(s7[off]);
    }
}

// input-side weight slices for the batched precompute
__global__ __launch_bounds__(256) void k_packX(const float* __restrict__ w_ih1,
                                               const float* __restrict__ s_wx,
                                               u16* __restrict__ W1X, u16* __restrict__ WSX) {
    int i = blockIdx.x * 256 + threadIdx.x;
    if (i < 2097152) {
        W1X[i] = f2bf(w_ih1[(size_t)(i >> 10) * 1536 + 512 + (i & 1023)]);
    } else if (i < 2621440) {
        int i2 = i - 2097152;
        WSX[i2] = f2bf(s_wx[(size_t)(i2 >> 10) * 1536 + 512 + (i2 & 1023)]);
    }
}

// gate-interleaved scan weights:
//  W1HS [2560][1024]: row' = (d>>4)*80 + g*16 + (d&15), g in {i,f,g,o,sent}, K=[h2|h1]
//  W2HS [2048][1024]: row' = (d>>4)*64 + g*16 + (d&15), K=[h1n|h2] (hidden side of LSTM2)
//  W2AS [2048][ 512]: row' = (d>>4)*64 + g*16 + (d&15), K=att (input side of LSTM2)
__global__ __launch_bounds__(256) void k_packS(
    const float* __restrict__ w_ih1, const float* __restrict__ w_hh1,
    const float* __restrict__ s_wx, const float* __restrict__ s_wh,
    const float* __restrict__ w_ih2, const float* __restrict__ w_hh2,
    u16* __restrict__ W1HS, u16* __restrict__ W2HS, u16* __restrict__ W2AS) {
    int i = blockIdx.x * 256 + threadIdx.x;
    if (i < 2621440) {
        int rp = i >> 10, k = i & 1023;
        int blk = rp / 80, rem = rp - blk * 80, g = rem >> 4, dl = rem & 15, d = blk * 16 + dl;
        float v;
        if (g < 4) v = (k < 512) ? w_ih1[(size_t)(g * 512 + d) * 1536 + k]
                                 : w_hh1[(size_t)(g * 512 + d) * 512 + (k - 512)];
        else       v = (k < 512) ? s_wx[(size_t)d * 1536 + k]
                                 : s_wh[(size_t)d * 512 + (k - 512)];
        W1HS[i] = f2bf(v);
    } else if (i < 2621440 + 2097152) {
        int i2 = i - 2621440;
        int rp = i2 >> 10, k = i2 & 1023;
        int blk = rp >> 6, rem = rp & 63, g = rem >> 4, dl = rem & 15, d = blk * 16 + dl;
        int row = g * 512 + d;
        float v = (k < 512) ? w_ih2[(size_t)row * 1024 + 512 + k]
                            : w_hh2[(size_t)row * 512 + (k - 512)];
        W2HS[i2] = f2bf(v);
    } else if (i < 2621440 + 2097152 + 1048576) {
        int i3 = i - 2621440 - 2097152;
        int rp = i3 >> 9, k = i3 & 511;
        int blk = rp >> 6, rem = rp & 63, g = rem >> 4, dl = rem & 15, d = blk * 16 + dl;
        W2AS[i3] = f2bf(w_ih2[(size_t)(g * 512 + d) * 1024 + k]);
    }
}

// xw[t][b][k] : k<512 -> emb[cap[b][t]][k], else global_image[b][k-512]
__global__ __launch_bounds__(256) void k_xw(const float* __restrict__ emb, const float* __restrict__ gimg,
                                            const int* __restrict__ cap, u16* __restrict__ XW, int total) {
    int i = blockIdx.x * 256 + threadIdx.x;
    if (i >= total) return;
    int t = i >> 17;
    int rem = i & ((1 << 17) - 1);
    int b = rem >> 10, k = rem & 1023;
    float v = (k < 512) ? emb[(size_t)cap[b * 50 + t] * 512 + k] : gimg[b * 512 + (k - 512)];
    XW[i] = f2bf(v);
}

// ---------------- batched precompute GEMMs ----------------

__global__ __launch_bounds__(256) void k_p1ps(const u16* __restrict__ XW, const u16* __restrict__ W1X,
                                              const u16* __restrict__ WSX,
                                              const float* __restrict__ b_ih1, const float* __restrict__ b_hh1,
                                              const float* __restrict__ s_bx, const float* __restrict__ s_bh,
                                              float* __restrict__ P1, float* __restrict__ PS) {
    int bid = blockIdx.x;
    int ng = bid % 40, mg = bid / 40;
    int w = threadIdx.x >> 6, lane = threadIdx.x & 63, r = lane & 15, lg = lane >> 4;
    int m_base = mg * 128 + w * 32;
    f32x4 acc[2][4] = {};
    if (ng < 32) {
        int n_base = ng * 64;
        gemm_2x4(XW, XW, 1 << 28, 1024, 1024, W1X, 1024, 1024, m_base, n_base, 4, acc);
#pragma unroll
        for (int mt = 0; mt < 2; ++mt)
#pragma unroll
            for (int j = 0; j < 4; ++j)
#pragma unroll
                for (int reg = 0; reg < 4; ++reg) {
                    int row = m_base + mt * 16 + lg * 4 + reg;
                    int col = n_base + j * 16 + r;
                    P1[(size_t)row * 2048 + col] = acc[mt][j][reg] + b_ih1[col] + b_hh1[col];
                }
    } else {
        int n_base = (ng - 32) * 64;
        gemm_2x4(XW, XW, 1 << 28, 1024, 1024, WSX, 1024, 1024, m_base, n_base, 4, acc);
#pragma unroll
        for (int mt = 0; mt < 2; ++mt)
#pragma unroll
            for (int j = 0; j < 4; ++j)
#pragma unroll
                for (int reg = 0; reg < 4; ++reg) {
                    int row = m_base + mt * 16 + lg * 4 + reg;
                    int col = n_base + j * 16 + r;
                    PS[(size_t)row * 512 + col] = acc[mt][j][reg] + s_bx[col] + s_bh[col];
                }
    }
}

__global__ __launch_bounds__(256) void k_va(const u16* __restrict__ SPB, const u16* __restrict__ WVB,
                                            const float* __restrict__ wv_b, float* __restrict__ VA) {
    int bid = blockIdx.x;
    int ng = bid % 8, mg = bid / 8;
    int w = threadIdx.x >> 6, lane = threadIdx.x & 63, r = lane & 15, lg = lane >> 4;
    int m_base = mg * 128 + w * 32;
    int n_base = ng * 64;
    f32x4 acc[2][4] = {};
    gemm_2x4(SPB, SPB, 1 << 28, 512, 512, WVB, 512, 512, m_base, n_base, 4, acc);
#pragma unroll
    for (int mt = 0; mt < 2; ++mt)
#pragma unroll
        for (int j = 0; j < 4; ++j)
#pragma unroll
            for (int reg = 0; reg < 4; ++reg) {
                int row = m_base + mt * 16 + lg * 4 + reg;
                int col = n_base + j * 16 + r;
                VA[(size_t)row * 512 + col] = acc[mt][j][reg] + wv_b[col];
            }
}

// ---------------- persistent scan phase bodies ----------------

// P1: LSTM1 + sentinel gate. 32 blocks = 4 rowg x 8 colg (colg owns 64 d, 5 gates).
__device__ __forceinline__ void p1_lstm1(int bid, const u16* H2BF, const u16* H1C,
                                         const u16* __restrict__ W1HS,
                                         const float* __restrict__ P1, const float* __restrict__ PS,
                                         float* M1, u16* H1N, u16* STBF, int t, u16* lds) {
    int rowg = bid >> 3, colg = bid & 7;
    stageA<1024>(lds, H2BF, H1C, 512, 512, 512, rowg * 32);
    int w = threadIdx.x >> 6, lane = threadIdx.x & 63, r = lane & 15, lg = lane >> 4;
    f32x4 acc[2][5] = {};
    gemm_lds<5, 1024>(lds, W1HS, colg * 320 + w * 80, acc);
    int d = colg * 64 + w * 16 + r;
#pragma unroll
    for (int mt = 0; mt < 2; ++mt)
#pragma unroll
        for (int reg = 0; reg < 4; ++reg) {
            int lrow = mt * 16 + lg * 4 + reg;
            int row = rowg * 32 + lrow;
            const float* p1r = P1 + ((size_t)t * 128 + row) * 2048;
            float gi = acc[mt][0][reg] + p1r[d];
            float gf = acc[mt][1][reg] + p1r[512 + d];
            float gg = acc[mt][2][reg] + p1r[1024 + d];
            float go = acc[mt][3][reg] + p1r[1536 + d];
            float gs = acc[mt][4][reg] + PS[((size_t)t * 128 + row) * 512 + d];
            int pidx = bid * 2048 + lrow * 64 + (w * 16 + r);
            float m1n = sigm(gf) * M1[pidx] + sigm(gi) * tanh_(gg);
            M1[pidx] = m1n;
            float tm = tanh_(m1n);
            st16(H1N + row * 512 + d, f2bf(sigm(go) * tm));
            st16(STBF + row * 512 + d, f2bf(sigm(gs) * tm));
        }
}

// P2a/b: chained GEMM pair (SRC -> act -> LDS-B [+globals] -> GEMM2 -> OUT).
__device__ __forceinline__ void p2_chain(int rowg, const u16* SRC,
                                         const u16* __restrict__ Wa, const float* __restrict__ ba,
                                         bool isrelu,
                                         const u16* __restrict__ Wb, const float* __restrict__ bb,
                                         u16* S2G, float* HTFG, float* OUT, u16* lds) {
    u16* ldsB = lds + 16384;
    stageA<512>(lds, SRC, SRC, 1 << 28, 512, 512, rowg * 32);
    int w = threadIdx.x >> 6, lane = threadIdx.x & 63, r = lane & 15, lg = lane >> 4;
    {
        f32x4 acc[2][8] = {};
        gemm_lds<8, 512>(lds, Wa, w * 128, acc);
#pragma unroll
        for (int mt = 0; mt < 2; ++mt)
#pragma unroll
            for (int j = 0; j < 8; ++j)
#pragma unroll
                for (int reg = 0; reg < 4; ++reg) {
                    int lrow = mt * 16 + lg * 4 + reg;
                    int col = (w * 128 + j * 16 + r);
                    float v = acc[mt][j][reg] + ba[col];
                    v = isrelu ? fmaxf(v, 0.f) : tanh_(v);
                    u16 hv = f2bf(v);
                    int cc = col >> 3, sw = cc ^ (lrow & 7);
                    ldsB[(lrow * 64 + sw) * 8 + (col & 7)] = hv;
                    int row = rowg * 32 + lrow;
                    if (isrelu) st16(S2G + row * 512 + col, hv);
                    else        st32(HTFG + row * 512 + col, v);
                }
    }
    __syncthreads();
    {
        f32x4 acc[2][8] = {};
        gemm_lds<8, 512>(ldsB, Wb, w * 128, acc);
#pragma unroll
        for (int mt = 0; mt < 2; ++mt)
#pragma unroll
            for (int j = 0; j < 8; ++j)
#pragma unroll
                for (int reg = 0; reg < 4; ++reg) {
                    int row = rowg * 32 + mt * 16 + lg * 4 + reg;
                    int col = w * 128 + j * 16 + r;
                    st32(OUT + row * 512 + col, acc[mt][j][reg] + bb[col]);
                }
    }
}

// P2c: g2p = [h1n|h2] @ W2HS^T (hidden side of LSTM2), gate-interleaved cols.
__device__ __forceinline__ void p2_g2p(int sb, const u16* H1N, const u16* H2BF,
                                       const u16* __restrict__ W2HS, float* G2P, u16* lds) {
    int rowg = sb >> 3, colg = sb & 7;
    stageA<1024>(lds, H1N, H2BF, 512, 512, 512, rowg * 32);
    int w = threadIdx.x >> 6, lane = threadIdx.x & 63, r = lane & 15, lg = lane >> 4;
    f32x4 acc[2][4] = {};
    gemm_lds<4, 1024>(lds, W2HS, colg * 256 + w * 64, acc);
    int d = colg * 64 + w * 16 + r;
#pragma unroll
    for (int mt = 0; mt < 2; ++mt)
#pragma unroll
        for (int j = 0; j < 4; ++j)
#pragma unroll
            for (int reg = 0; reg < 4; ++reg) {
                int row = rowg * 32 + mt * 16 + lg * 4 + reg;
                st32(G2P + (size_t)row * 2048 + j * 512 + d, acc[mt][j][reg]);
            }
}

// P3: adaptive attention for one batch row.
__device__ __forceinline__ void p3_attn(int b, const float* __restrict__ VA, const float* SEN,
                                        const float* HID, const float* __restrict__ whw,
                                        const float* __restrict__ whb, const float* __restrict__ SF,
                                        const u16* S2BF, const float* HTF, u16* CHHBF,
                                        float* hidL, float* whwL, float* zbuf, float* albuf) {
    int tid = threadIdx.x;
    for (int i = tid; i < 512; i += 256) { hidL[i] = ld32(HID + b * 512 + i); whwL[i] = whw[i]; }
    __syncthreads();
    int w = tid >> 6, lane = tid & 63;
    for (int p = w; p < 50; p += 4) {
        float part = 0.f;
        if (p < 49) {
            const float* src = VA + ((size_t)b * 49 + p) * 512;
#pragma unroll
            for (int it = 0; it < 8; ++it) {
                int a = lane + it * 64;
                part += tanh_(src[a] + hidL[a]) * whwL[a];
            }
        } else {
#pragma unroll
            for (int it = 0; it < 8; ++it) {
                int a = lane + it * 64;
                part += tanh_(ld32(SEN + (size_t)b * 512 + a) + hidL[a]) * whwL[a];
            }
        }
#pragma unroll
        for (int o = 32; o; o >>= 1) part += __shfl_xor(part, o, 64);
        if (lane == 0) zbuf[p] = part + whb[0];
    }
    __syncthreads();
    if (tid < 64) {
        float v = (tid < 50) ? zbuf[tid] : -1e30f;
        float mx = v;
#pragma unroll
        for (int o = 32; o; o >>= 1) mx = fmaxf(mx, __shfl_xor(mx, o, 64));
        float e = (tid < 50) ? __expf(v - mx) : 0.f;
        float s = e;
#pragma unroll
        for (int o = 32; o; o >>= 1) s += __shfl_xor(s, o, 64);
        if (tid < 50) albuf[tid] = e / s;
    }
    __syncthreads();
    float a49 = albuf[49];
    {
        int d2 = tid * 2;
        unsigned s2p = ld32u(S2BF + (size_t)b * 512 + d2);
        float acc0 = a49 * bf2f((u16)(s2p & 0xffffu));
        float acc1 = a49 * bf2f((u16)(s2p >> 16));
        for (int p = 0; p < 49; ++p) {
            const float* sf = SF + ((size_t)b * 49 + p) * 512 + d2;
            float al = albuf[p];
            acc0 += al * sf[0];
            acc1 += al * sf[1];
        }
        acc0 += ld32(HTF + (size_t)b * 512 + d2);
        acc1 += ld32(HTF + (size_t)b * 512 + d2 + 1);
        unsigned pk = (unsigned)f2bf(acc0) | ((unsigned)f2bf(acc1) << 16);
        st32u(CHHBF + (size_t)b * 512 + d2, pk);
    }
    __syncthreads();
}

// P4: chh -> att (redundant per rowg, in LDS) -> LSTM2 cell update.
__device__ __forceinline__ void p4_lstm2(int bid, const u16* CHHBF,
                                         const u16* __restrict__ WPB, const float* __restrict__ wp_b,
                                         const u16* __restrict__ W2AS, const float* G2P,
                                         const float* __restrict__ b_ih2, const float* __restrict__ b_hh2,
                                         float* M2, u16* H2BF, u16* H2ALL, int t, u16* lds) {
    int rowg = bid >> 3, colg = bid & 7;
    u16* ldsB = lds + 16384;
    stageA<512>(lds, CHHBF, CHHBF, 1 << 28, 512, 512, rowg * 32);
    int w = threadIdx.x >> 6, lane = threadIdx.x & 63, r = lane & 15, lg = lane >> 4;
    {
        f32x4 acc[2][8] = {};
        gemm_lds<8, 512>(lds, WPB, w * 128, acc);
#pragma unroll
        for (int mt = 0; mt < 2; ++mt)
#pragma unroll
            for (int j = 0; j < 8; ++j)
#pragma unroll
                for (int reg = 0; reg < 4; ++reg) {
                    int lrow = mt * 16 + lg * 4 + reg;
                    int col = w * 128 + j * 16 + r;
                    u16 hv = f2bf(tanh_(acc[mt][j][reg] + wp_b[col]));
                    int cc = col >> 3, sw = cc ^ (lrow & 7);
                    ldsB[(lrow * 64 + sw) * 8 + (col & 7)] = hv;
                }
    }
    __syncthreads();
    {
        f32x4 acc[2][4] = {};
        gemm_lds<4, 512>(ldsB, W2AS, colg * 256 + w * 64, acc);
        int d = colg * 64 + w * 16 + r;
#pragma unroll
        for (int mt = 0; mt < 2; ++mt)
#pragma unroll
            for (int reg = 0; reg < 4; ++reg) {
                int lrow = mt * 16 + lg * 4 + reg;
                int row = rowg * 32 + lrow;
                const float* g2r = G2P + (size_t)row * 2048;
                float gi = acc[mt][0][reg] + ld32(g2r + d)        + b_ih2[d]        + b_hh2[d];
                float gf = acc[mt][1][reg] + ld32(g2r + 512 + d)  + b_ih2[512 + d]  + b_hh2[512 + d];
                float gg = acc[mt][2][reg] + ld32(g2r + 1024 + d) + b_ih2[1024 + d] + b_hh2[1024 + d];
                float go = acc[mt][3][reg] + ld32(g2r + 1536 + d) + b_ih2[1536 + d] + b_hh2[1536 + d];
                int pidx = bid * 2048 + lrow * 64 + (w * 16 + r);
                float m2n = sigm(gf) * M2[pidx] + sigm(gi) * tanh_(gg);
                M2[pidx] = m2n;
                u16 hb = f2bf(sigm(go) * tanh_(m2n));
                st16(H2BF + row * 512 + d, hb);
                st16(H2ALL + ((size_t)t * 128 + row) * 512 + d, hb);
            }
    }
}

__global__ __launch_bounds__(256) void k_scan(
    const u16* __restrict__ W1HS, const u16* __restrict__ W2HS, const u16* __restrict__ W2AS,
    const u16* __restrict__ AFFS, const u16* __restrict__ AFFH,
    const u16* __restrict__ WSB, const u16* __restrict__ WGB, const u16* __restrict__ WPB,
    const float* __restrict__ P1, const float* __restrict__ PS, const float* __restrict__ VA,
    const float* __restrict__ b_ih2, const float* __restrict__ b_hh2,
    const float* __restrict__ affs_b, const float* __restrict__ affh_b,
    const float* __restrict__ wg_b, const float* __restrict__ ws_b, const float* __restrict__ wp_b,
    const float* __restrict__ whw, const float* __restrict__ whb, const float* __restrict__ SF,
    u16* H1A, u16* H1B, u16* H2BF, u16* STBF, u16* S2BF, u16* CHHBF,
    float* M1, float* M2, float* HTF, float* HID, float* SEN, float* G2P,
    u16* H2ALL, int* bar) {
    union SmemU {
        ull stage[8192];  // 64 KiB: A half (32K) + B half (32K)
        struct { float hidL[512], whwL[512], zbuf[64], albuf[64]; } att;
    };
    __shared__ SmemU sm;
    u16* lds = (u16*)sm.stage;
    int bid = blockIdx.x;
    int bi = 0;
    for (int t = 0; t < 49; ++t) {
        const u16* h1c = (t & 1) ? H1B : H1A;
        u16* h1n = (t & 1) ? H1A : H1B;
        if (bid < 32) p1_lstm1(bid, H2BF, h1c, W1HS, P1, PS, M1, h1n, STBF, t, lds);
        grid_barrier(bar, bi++);
        if (bid < 4)       p2_chain(bid, STBF, AFFS, affs_b, true,  WSB, ws_b, S2BF, HTF, SEN, lds);
        else if (bid < 8)  p2_chain(bid - 4, h1n, AFFH, affh_b, false, WGB, wg_b, S2BF, HTF, HID, lds);
        else if (bid < 40) p2_g2p(bid - 8, h1n, H2BF, W2HS, G2P, lds);
        grid_barrier(bar, bi++);
        p3_attn(bid, VA, SEN, HID, whw, whb, SF, S2BF, HTF, CHHBF,
                sm.att.hidL, sm.att.whwL, sm.att.zbuf, sm.att.albuf);
        p3_attn(bid + 64, VA, SEN, HID, whw, whb, SF, S2BF, HTF, CHHBF,
                sm.att.hidL, sm.att.whwL, sm.att.zbuf, sm.att.albuf);
        grid_barrier(bar, bi++);
        if (bid < 32) p4_lstm2(bid, CHHBF, WPB, wp_b, W2AS, G2P, b_ih2, b_hh2, M2, H2BF, H2ALL, t, lds);
        grid_barrier(bar, bi++);
    }
}

// Final: preds[b][t][v] = H2all[t*128+b] @ fc_w^T + fc_b
__global__ __launch_bounds__(256) void k_fc(const u16* __restrict__ H2ALL, const u16* __restrict__ FCB,
                                            const float* __restrict__ fc_b, float* __restrict__ out) {
    int bid = blockIdx.x;
    int ng = bid % 157, mg = bid / 157;
    int w = threadIdx.x >> 6, lane = threadIdx.x & 63, r = lane & 15, lg = lane >> 4;
    int m_base = mg * 128 + w * 32;
    int n_base = ng * 64;
    int nt = (10000 - n_base) / 16; if (nt > 4) nt = 4;
    f32x4 acc[2][4] = {};
    gemm_2x4(H2ALL, H2ALL, 1 << 28, 512, 512, FCB, 512, 512, m_base, n_base, nt, acc);
#pragma unroll
    for (int mt = 0; mt < 2; ++mt)
#pragma unroll
        for (int j = 0; j < 4; ++j) {
            if (j < nt) {
#pragma unroll
                for (int reg = 0; reg < 4; ++reg) {
                    int row = m_base + mt * 16 + lg * 4 + reg;
                    int col = n_base + j * 16 + r;
                    int t = row >> 7, b = row & 127;
                    out[((size_t)b * 49 + t) * 10000 + col] = acc[mt][j][reg] + fc_b[col];
                }
            }
        }
}

// ---------------------------------------------------------------------------

extern "C" void kernel_launch(void* const* d_in, const int* in_sizes, int n_in,
                              void* d_out, int out_size, void* d_ws, size_t ws_size,
                              hipStream_t stream) {
    (void)in_sizes; (void)n_in; (void)out_size; (void)ws_size;

    const float* SF      = (const float*)d_in[0];
    const float* GIMG    = (const float*)d_in[1];
    const int*   CAP     = (const int*)d_in[2];
    const float* EMB     = (const float*)d_in[4];
    const float* w_ih1   = (const float*)d_in[5];
    const float* w_hh1   = (const float*)d_in[6];
    const float* b_ih1   = (const float*)d_in[7];
    const float* b_hh1   = (const float*)d_in[8];
    const float* s_wx    = (const float*)d_in[9];
    const float* s_bx    = (const float*)d_in[10];
    const float* s_wh    = (const float*)d_in[11];
    const float* s_bh    = (const float*)d_in[12];
    const float* w_ih2   = (const float*)d_in[13];
    const float* w_hh2   = (const float*)d_in[14];
    const float* b_ih2   = (const float*)d_in[15];
    const float* b_hh2   = (const float*)d_in[16];
    const float* aff_s_w = (const float*)d_in[17];
    const float* aff_s_b = (const float*)d_in[18];
    const float* aff_h_w = (const float*)d_in[19];
    const float* aff_h_b = (const float*)d_in[20];
    const float* ws_w    = (const float*)d_in[21];
    const float* ws_b    = (const float*)d_in[22];
    const float* wg_w    = (const float*)d_in[23];
    const float* wg_b    = (const float*)d_in[24];
    const float* wv_w    = (const float*)d_in[25];
    const float* wv_b    = (const float*)d_in[26];
    const float* wh_w    = (const float*)d_in[27];
    const float* wh_b    = (const float*)d_in[28];
    const float* wp_w    = (const float*)d_in[29];
    const float* wp_b    = (const float*)d_in[30];
    const float* fc_w    = (const float*)d_in[31];
    const float* fc_b    = (const float*)d_in[32];

    float* out = (float*)d_out;

    // big fp32 scratch lives in d_out (fc overwrites all of d_out at the end)
    float* P1 = out;                      // 49*128*2048
    float* PS = out + 12845056;           // 49*128*512
    float* VA = out + 16056320;           // 128*49*512

    char* ws = (char*)d_ws;
    size_t off = 0;
    auto alloc = [&](size_t elts, size_t esz) -> void* {
        void* p = ws + off;
        off += (elts * esz + 255) & ~(size_t)255;
        return p;
    };
    u16* W1HS  = (u16*)alloc(2621440, 2);
    u16* W2HS  = (u16*)alloc(2097152, 2);
    u16* W2AS  = (u16*)alloc(1048576, 2);
    u16* W1X   = (u16*)alloc(2097152, 2);
    u16* WSX   = (u16*)alloc(524288, 2);
    u16* AFFS  = (u16*)alloc(262144, 2);
    u16* AFFH  = (u16*)alloc(262144, 2);
    u16* WSB   = (u16*)alloc(262144, 2);
    u16* WGB   = (u16*)alloc(262144, 2);
    u16* WVB   = (u16*)alloc(262144, 2);
    u16* WPB   = (u16*)alloc(262144, 2);
    u16* FCB   = (u16*)alloc(5120000, 2);
    u16* SPB   = (u16*)alloc(3211264, 2);
    u16* XWB   = (u16*)alloc(6422528, 2);
    u16* H2ALL = (u16*)alloc(3211264, 2);
    u16* H1A   = (u16*)alloc(65536, 2);
    u16* H1B   = (u16*)alloc(65536, 2);
    u16* H2BF  = (u16*)alloc(65536, 2);
    u16* STBF  = (u16*)alloc(65536, 2);
    u16* S2BF  = (u16*)alloc(65536, 2);
    u16* CHHBF = (u16*)alloc(65536, 2);
    float* M1  = (float*)alloc(65536, 4);
    float* M2  = (float*)alloc(65536, 4);
    float* HTF = (float*)alloc(65536, 4);
    float* HID = (float*)alloc(65536, 4);
    float* SEN = (float*)alloc(65536, 4);
    float* G2P = (float*)alloc(262144, 4);
    int*   BAR = (int*)alloc(2048, 4);

    // zero-init recurrent state + barrier counters (every call / replay)
    hipMemsetAsync(H1A, 0, 65536 * 2, stream);
    hipMemsetAsync(H2BF, 0, 65536 * 2, stream);
    hipMemsetAsync(M1, 0, 65536 * 4, stream);
    hipMemsetAsync(M2, 0, 65536 * 4, stream);
    hipMemsetAsync(BAR, 0, 2048 * 4, stream);

    // prep: conversions + packs + xw gather
    k_cvt8<<<38688, 256, 0, stream>>>(aff_s_w, aff_h_w, ws_w, wg_w, wv_w, wp_w, fc_w, SF,
                                      AFFS, AFFH, WSB, WGB, WVB, WPB, FCB, SPB);
    k_packX<<<(2621440 + 255) / 256, 256, 0, stream>>>(w_ih1, s_wx, W1X, WSX);
    k_packS<<<(5767168 + 255) / 256, 256, 0, stream>>>(w_ih1, w_hh1, s_wx, s_wh, w_ih2, w_hh2,
                                                       W1HS, W2HS, W2AS);
    k_xw<<<(6422528 + 255) / 256, 256, 0, stream>>>(EMB, GIMG, CAP, XWB, 6422528);

    // batched precompute GEMMs
    k_p1ps<<<49 * 40, 256, 0, stream>>>(XWB, W1X, WSX, b_ih1, b_hh1, s_bx, s_bh, P1, PS);
    k_va<<<49 * 8, 256, 0, stream>>>(SPB, WVB, wv_b, VA);

    // persistent sequential scan (64 co-resident blocks, fence-free barriers)
    k_scan<<<NBLK, 256, 0, stream>>>(W1HS, W2HS, W2AS, AFFS, AFFH, WSB, WGB, WPB,
                                     P1, PS, VA, b_ih2, b_hh2, aff_s_b, aff_h_b,
                                     wg_b, ws_b, wp_b, wh_w, wh_b, SF,
                                     H1A, H1B, H2BF, STBF, S2BF, CHHBF,
                                     M1, M2, HTF, HID, SEN, G2P, H2ALL, BAR);

    // final projection to vocab
    k_fc<<<49 * 157, 256, 0, stream>>>(H2ALL, FCB, fc_b, out);
}

// Round 4
// 18058.833 us; speedup vs baseline: 1.1085x; 1.1085x over previous
//
#include <hip/hip_runtime.h>

// ---------------------------------------------------------------------------
// Adaptive-attention LSTM decoder (B=128, P=49, D=E=A=512, V=10000, T=50).
//  * Persistent scan kernel: 64 co-resident blocks, 4 phases/step, fence-free
//    grid barriers. Inter-phase vectors via cache-bypassing (sc0 sc1) access;
//    weights / SPB / VAB via normal cached loads, partitioned so each XCD's
//    slice (~4MB) stays L2-resident across all 49 steps.
//  * g2p partials park in LDS across the attention phase (same block computes
//    phase 2c and phase 4 with identical lane mapping) - no global round trip.
//  * LDS = 64KB static: [0:32K) A-stage / attn arrays, [32K:64K) park / ldsB.
//  * Precompute: P1/Ps (input-side gates), visual_att (bf16); final: fc GEMM.
// ---------------------------------------------------------------------------

typedef unsigned short u16;
typedef unsigned long long ull;
typedef short bf16x8 __attribute__((ext_vector_type(8)));
typedef float f32x4 __attribute__((ext_vector_type(4)));

#define MFMA16(a, b, c) __builtin_amdgcn_mfma_f32_16x16x32_bf16(a, b, c, 0, 0, 0)
#define NBLK 64

__device__ __forceinline__ u16 f2bf(float f) {
    union { float f; unsigned u; } v; v.f = f;
    return (u16)((v.u + 0x7fffu + ((v.u >> 16) & 1u)) >> 16);
}
__device__ __forceinline__ float bf2f(u16 h) {
    union { unsigned u; float f; } v; v.u = ((unsigned)h) << 16; return v.f;
}
__device__ __forceinline__ float sigm(float x) {
    x = fminf(fmaxf(x, -30.f), 30.f);
    return 1.f / (1.f + __expf(-x));
}
__device__ __forceinline__ float tanh_(float x) {
    x = fminf(fmaxf(x, -15.f), 15.f);
    float e = __expf(2.f * x);
    return (e - 1.f) / (e + 1.f);
}

// ---- agent-scope (cross-XCD coherent, cache-bypassing) accessors ----
__device__ __forceinline__ ull ldq(const u16* p) {
    return __hip_atomic_load((const ull*)p, __ATOMIC_RELAXED, __HIP_MEMORY_SCOPE_AGENT);
}
__device__ __forceinline__ float ld32(const float* p) {
    return __hip_atomic_load(p, __ATOMIC_RELAXED, __HIP_MEMORY_SCOPE_AGENT);
}
__device__ __forceinline__ unsigned ld32u(const u16* p) {
    return __hip_atomic_load((const unsigned*)p, __ATOMIC_RELAXED, __HIP_MEMORY_SCOPE_AGENT);
}
__device__ __forceinline__ void st32(float* p, float v) {
    __hip_atomic_store(p, v, __ATOMIC_RELAXED, __HIP_MEMORY_SCOPE_AGENT);
}
__device__ __forceinline__ void st32u(u16* p, unsigned v) {
    __hip_atomic_store((unsigned*)p, v, __ATOMIC_RELAXED, __HIP_MEMORY_SCOPE_AGENT);
}
__device__ __forceinline__ void st16(u16* p, u16 v) {
    asm volatile("global_store_short %0, %1, off sc0 sc1" :: "v"(p), "v"((unsigned)v) : "memory");
}

// Fence-free grid barrier: drain own bypass stores, count arrivals.
__device__ __forceinline__ void grid_barrier(int* bar, int idx) {
    asm volatile("s_waitcnt vmcnt(0)" ::: "memory");
    __syncthreads();
    if (threadIdx.x == 0) {
        __hip_atomic_fetch_add(&bar[idx], 1, __ATOMIC_RELAXED, __HIP_MEMORY_SCOPE_AGENT);
        while (__hip_atomic_load(&bar[idx], __ATOMIC_RELAXED, __HIP_MEMORY_SCOPE_AGENT) < NBLK)
            __builtin_amdgcn_s_sleep(1);
    }
    __syncthreads();
    asm volatile("" ::: "memory");
}

// ---- LDS A-staging: 32 rows x 512 bf16 (32KB), XOR-swizzled 16B chunks ----
__device__ __forceinline__ void stage512(u16* lds, const u16* SRC, int r0) {
    __syncthreads();  // protect previous contents' readers
    ull t0[8], t1[8];
#pragma unroll
    for (int j = 0; j < 8; ++j) {
        int c = j * 256 + (int)threadIdx.x;
        int row = c >> 6, cc = c & 63;
        const u16* src = SRC + (size_t)(r0 + row) * 512 + cc * 8;
        t0[j] = ldq(src);
        t1[j] = ldq(src + 4);
    }
    __builtin_amdgcn_sched_barrier(0);
#pragma unroll
    for (int j = 0; j < 8; ++j) {
        int c = j * 256 + (int)threadIdx.x;
        int row = c >> 6, cc = c & 63;
        int sw = cc ^ (row & 7);
        ull* dst = (ull*)(lds + ((row * 64 + sw) << 3));
        dst[0] = t0[j];
        dst[1] = t1[j];
    }
    __syncthreads();
}

__device__ __forceinline__ bf16x8 ldsA512(const u16* lds, int row, int kk) {
    int cc = kk >> 3;
    int sw = cc ^ (row & 7);
    return *(const bf16x8*)(lds + ((row * 64 + sw) << 3));
}

// Wave computes 2 m-tiles x NT n-tiles over K=512; A from swizzled LDS,
// W row-major [N][ldw] cached loads at column offset koff.
template<int NT>
__device__ __forceinline__ void gemm512(const u16* lds, const u16* __restrict__ W,
                                        int ldw, int koff, int n_base, f32x4 acc[2][NT]) {
    const int lane = threadIdx.x & 63, r = lane & 15, lg = lane >> 4;
    for (int k0 = 0; k0 < 512; k0 += 32) {
        int kk = k0 + lg * 8;
        bf16x8 a0 = ldsA512(lds, r, kk);
        bf16x8 a1 = ldsA512(lds, 16 + r, kk);
#pragma unroll
        for (int j = 0; j < NT; ++j) {
            bf16x8 wf = *(const bf16x8*)(W + (size_t)(n_base + j * 16 + r) * ldw + koff + kk);
            acc[0][j] = MFMA16(a0, wf, acc[0][j]);
            acc[1][j] = MFMA16(a1, wf, acc[1][j]);
        }
    }
}

// Plain-global-A gemm (pre/post kernels only).
__device__ __forceinline__ void gemm_2x4(const u16* __restrict__ A0, const u16* __restrict__ A1,
                                         int asplit, int lda0, int lda1,
                                         const u16* __restrict__ W, int ldw, int K,
                                         int m_base, int n_base, int nt, f32x4 acc[2][4]) {
    const int lane = threadIdx.x & 63, r = lane & 15, lg = lane >> 4;
    for (int k0 = 0; k0 < K; k0 += 32) {
        int kk = k0 + lg * 8;
        const u16* Ab; int ka, lda;
        if (k0 < asplit) { Ab = A0; ka = kk; lda = lda0; }
        else             { Ab = A1; ka = kk - asplit; lda = lda1; }
        bf16x8 a0 = *(const bf16x8*)(Ab + (size_t)(m_base + r) * lda + ka);
        bf16x8 a1 = *(const bf16x8*)(Ab + (size_t)(m_base + 16 + r) * lda + ka);
#pragma unroll
        for (int j = 0; j < 4; ++j) {
            if (j < nt) {
                bf16x8 wf = *(const bf16x8*)(W + (size_t)(n_base + j * 16 + r) * ldw + kk);
                acc[0][j] = MFMA16(a0, wf, acc[0][j]);
                acc[1][j] = MFMA16(a1, wf, acc[1][j]);
            }
        }
    }
}

// ---------------- one-time conversion / packing kernels ----------------

__global__ __launch_bounds__(256) void k_cvt8(
    const float* __restrict__ s0, const float* __restrict__ s1, const float* __restrict__ s2,
    const float* __restrict__ s3, const float* __restrict__ s4, const float* __restrict__ s5,
    const float* __restrict__ s6, const float* __restrict__ s7,
    u16* __restrict__ d0, u16* __restrict__ d1, u16* __restrict__ d2, u16* __restrict__ d3,
    u16* __restrict__ d4, u16* __restrict__ d5, u16* __restrict__ d6, u16* __restrict__ d7) {
    int i = blockIdx.x * 256 + threadIdx.x;
    const int S = 262144;
    if (i < 6 * S) {
        int seg = i >> 18, off = i & (S - 1);
        const float* s = seg == 0 ? s0 : seg == 1 ? s1 : seg == 2 ? s2 : seg == 3 ? s3 : seg == 4 ? s4 : s5;
        u16* d = seg == 0 ? d0 : seg == 1 ? d1 : seg == 2 ? d2 : seg == 3 ? d3 : seg == 4 ? d4 : d5;
        d[off] = f2bf(s[off]);
    } else if (i < 6 * S + 5120000) {
        int off = i - 6 * S;
        d6[off] = f2bf(s6[off]);
    } else {
        int off = i - 6 * S - 5120000;
        if (off < 3211264) d7[off] = f2bf(s7[off]);
    }
}

// input-side weight slices for the batched precompute
__global__ __launch_bounds__(256) void k_packX(const float* __restrict__ w_ih1,
                                               const float* __restrict__ s_wx,
                                               u16* __restrict__ W1X, u16* __restrict__ WSX) {
    int i = blockIdx.x * 256 + threadIdx.x;
    if (i < 2097152) {
        W1X[i] = f2bf(w_ih1[(size_t)(i >> 10) * 1536 + 512 + (i & 1023)]);
    } else if (i < 2621440) {
        int i2 = i - 2097152;
        WSX[i2] = f2bf(s_wx[(size_t)(i2 >> 10) * 1536 + 512 + (i2 & 1023)]);
    }
}

// gate-interleaved scan weights:
//  W1HS [2560][1024]: row' = (d>>4)*80 + g*16 + (d&15), g in {i,f,g,o,sent}, K=[h2|h1]
//  W2HS [2048][1024]: row' = (d>>4)*64 + g*16 + (d&15), K=[h1n|h2] (hidden side LSTM2)
//  W2AS [2048][ 512]: row' = (d>>4)*64 + g*16 + (d&15), K=att (input side LSTM2)
__global__ __launch_bounds__(256) void k_packS(
    const float* __restrict__ w_ih1, const float* __restrict__ w_hh1,
    const float* __restrict__ s_wx, const float* __restrict__ s_wh,
    const float* __restrict__ w_ih2, const float* __restrict__ w_hh2,
    u16* __restrict__ W1HS, u16* __restrict__ W2HS, u16* __restrict__ W2AS) {
    int i = blockIdx.x * 256 + threadIdx.x;
    if (i < 2621440) {
        int rp = i >> 10, k = i & 1023;
        int blk = rp / 80, rem = rp - blk * 80, g = rem >> 4, dl = rem & 15, d = blk * 16 + dl;
        float v;
        if (g < 4) v = (k < 512) ? w_ih1[(size_t)(g * 512 + d) * 1536 + k]
                                 : w_hh1[(size_t)(g * 512 + d) * 512 + (k - 512)];
        else       v = (k < 512) ? s_wx[(size_t)d * 1536 + k]
                                 : s_wh[(size_t)d * 512 + (k - 512)];
        W1HS[i] = f2bf(v);
    } else if (i < 2621440 + 2097152) {
        int i2 = i - 2621440;
        int rp = i2 >> 10, k = i2 & 1023;
        int blk = rp >> 6, rem = rp & 63, g = rem >> 4, dl = rem & 15, d = blk * 16 + dl;
        int row = g * 512 + d;
        float v = (k < 512) ? w_ih2[(size_t)row * 1024 + 512 + k]
                            : w_hh2[(size_t)row * 512 + (k - 512)];
        W2HS[i2] = f2bf(v);
    } else if (i < 2621440 + 2097152 + 1048576) {
        int i3 = i - 2621440 - 2097152;
        int rp = i3 >> 9, k = i3 & 511;
        int blk = rp >> 6, rem = rp & 63, g = rem >> 4, dl = rem & 15, d = blk * 16 + dl;
        W2AS[i3] = f2bf(w_ih2[(size_t)(g * 512 + d) * 1024 + k]);
    }
}

// xw[t][b][k] : k<512 -> emb[cap[b][t]][k], else global_image[b][k-512]
__global__ __launch_bounds__(256) void k_xw(const float* __restrict__ emb, const float* __restrict__ gimg,
                                            const int* __restrict__ cap, u16* __restrict__ XW, int total) {
    int i = blockIdx.x * 256 + threadIdx.x;
    if (i >= total) return;
    int t = i >> 17;
    int rem = i & ((1 << 17) - 1);
    int b = rem >> 10, k = rem & 1023;
    float v = (k < 512) ? emb[(size_t)cap[b * 50 + t] * 512 + k] : gimg[b * 512 + (k - 512)];
    XW[i] = f2bf(v);
}

// ---------------- batched precompute GEMMs ----------------

__global__ __launch_bounds__(256) void k_p1ps(const u16* __restrict__ XW, const u16* __restrict__ W1X,
                                              const u16* __restrict__ WSX,
                                              const float* __restrict__ b_ih1, const float* __restrict__ b_hh1,
                                              const float* __restrict__ s_bx, const float* __restrict__ s_bh,
                                              float* __restrict__ P1, float* __restrict__ PS) {
    int bid = blockIdx.x;
    int ng = bid % 40, mg = bid / 40;
    int w = threadIdx.x >> 6, lane = threadIdx.x & 63, r = lane & 15, lg = lane >> 4;
    int m_base = mg * 128 + w * 32;
    f32x4 acc[2][4] = {};
    if (ng < 32) {
        int n_base = ng * 64;
        gemm_2x4(XW, XW, 1 << 28, 1024, 1024, W1X, 1024, 1024, m_base, n_base, 4, acc);
#pragma unroll
        for (int mt = 0; mt < 2; ++mt)
#pragma unroll
            for (int j = 0; j < 4; ++j)
#pragma unroll
                for (int reg = 0; reg < 4; ++reg) {
                    int row = m_base + mt * 16 + lg * 4 + reg;
                    int col = n_base + j * 16 + r;
                    P1[(size_t)row * 2048 + col] = acc[mt][j][reg] + b_ih1[col] + b_hh1[col];
                }
    } else {
        int n_base = (ng - 32) * 64;
        gemm_2x4(XW, XW, 1 << 28, 1024, 1024, WSX, 1024, 1024, m_base, n_base, 4, acc);
#pragma unroll
        for (int mt = 0; mt < 2; ++mt)
#pragma unroll
            for (int j = 0; j < 4; ++j)
#pragma unroll
                for (int reg = 0; reg < 4; ++reg) {
                    int row = m_base + mt * 16 + lg * 4 + reg;
                    int col = n_base + j * 16 + r;
                    PS[(size_t)row * 512 + col] = acc[mt][j][reg] + s_bx[col] + s_bh[col];
                }
    }
}

__global__ __launch_bounds__(256) void k_va(const u16* __restrict__ SPB, const u16* __restrict__ WVB,
                                            const float* __restrict__ wv_b, u16* __restrict__ VAB) {
    int bid = blockIdx.x;
    int ng = bid % 8, mg = bid / 8;
    int w = threadIdx.x >> 6, lane = threadIdx.x & 63, r = lane & 15, lg = lane >> 4;
    int m_base = mg * 128 + w * 32;
    int n_base = ng * 64;
    f32x4 acc[2][4] = {};
    gemm_2x4(SPB, SPB, 1 << 28, 512, 512, WVB, 512, 512, m_base, n_base, 4, acc);
#pragma unroll
    for (int mt = 0; mt < 2; ++mt)
#pragma unroll
        for (int j = 0; j < 4; ++j)
#pragma unroll
            for (int reg = 0; reg < 4; ++reg) {
                int row = m_base + mt * 16 + lg * 4 + reg;
                int col = n_base + j * 16 + r;
                VAB[(size_t)row * 512 + col] = f2bf(acc[mt][j][reg] + wv_b[col]);
            }
}

// ---------------- persistent scan phase bodies ----------------

// P1: LSTM1 + sentinel. 32 blocks = 4 rowg x 8 colg; colg==XCD -> stable L2 slice.
__device__ __forceinline__ void p1_lstm1(int bid, const u16* H2BF, const u16* H1C,
                                         const u16* __restrict__ W1HS,
                                         const float* __restrict__ P1, const float* __restrict__ PS,
                                         float* M1, u16* H1N, u16* STBF, int t, u16* lds) {
    int rowg = bid >> 3, colg = bid & 7;
    int w = threadIdx.x >> 6, lane = threadIdx.x & 63, r = lane & 15, lg = lane >> 4;
    f32x4 acc[2][5] = {};
    stage512(lds, H2BF, rowg * 32);
    gemm512<5>(lds, W1HS, 1024, 0, colg * 320 + w * 80, acc);
    stage512(lds, H1C, rowg * 32);
    gemm512<5>(lds, W1HS, 1024, 512, colg * 320 + w * 80, acc);
    int d = colg * 64 + w * 16 + r;
#pragma unroll
    for (int mt = 0; mt < 2; ++mt)
#pragma unroll
        for (int reg = 0; reg < 4; ++reg) {
            int lrow = mt * 16 + lg * 4 + reg;
            int row = rowg * 32 + lrow;
            const float* p1r = P1 + ((size_t)t * 128 + row) * 2048;
            float gi = acc[mt][0][reg] + p1r[d];
            float gf = acc[mt][1][reg] + p1r[512 + d];
            float gg = acc[mt][2][reg] + p1r[1024 + d];
            float go = acc[mt][3][reg] + p1r[1536 + d];
            float gs = acc[mt][4][reg] + PS[((size_t)t * 128 + row) * 512 + d];
            int pidx = bid * 2048 + lrow * 64 + (w * 16 + r);
            float m1n = sigm(gf) * M1[pidx] + sigm(gi) * tanh_(gg);
            M1[pidx] = m1n;
            float tm = tanh_(m1n);
            st16(H1N + row * 512 + d, f2bf(sigm(go) * tm));
            st16(STBF + row * 512 + d, f2bf(sigm(gs) * tm));
        }
}

// P2c: g2p = [h1n|h2] @ W2HS^T; partials parked in LDS (same block runs P4).
__device__ __forceinline__ void p2_g2p(int bid, const u16* H1N, const u16* H2BF,
                                       const u16* __restrict__ W2HS, float* park, u16* lds) {
    int rowg = bid >> 3, colg = bid & 7;
    int w = threadIdx.x >> 6;
    f32x4 acc[2][4] = {};
    stage512(lds, H1N, rowg * 32);
    gemm512<4>(lds, W2HS, 1024, 0, colg * 256 + w * 64, acc);
    stage512(lds, H2BF, rowg * 32);
    gemm512<4>(lds, W2HS, 1024, 512, colg * 256 + w * 64, acc);
#pragma unroll
    for (int mt = 0; mt < 2; ++mt)
#pragma unroll
        for (int j = 0; j < 4; ++j)
#pragma unroll
            for (int reg = 0; reg < 4; ++reg)
                park[(mt * 16 + j * 4 + reg) * 256 + threadIdx.x] = acc[mt][j][reg];
}

// P2a/b: chained GEMM pair (SRC -> act -> ldsB [+globals] -> GEMM2 -> OUT).
__device__ __forceinline__ void p2_chain(int rowg, const u16* SRC,
                                         const u16* __restrict__ Wa, const float* __restrict__ ba,
                                         bool isrelu,
                                         const u16* __restrict__ Wb, const float* __restrict__ bb,
                                         u16* S2G, float* HTFG, float* OUT, u16* lds) {
    u16* ldsB = lds + 16384;
    int w = threadIdx.x >> 6, lane = threadIdx.x & 63, r = lane & 15, lg = lane >> 4;
    stage512(lds, SRC, rowg * 32);
    {
        f32x4 acc[2][8] = {};
        gemm512<8>(lds, Wa, 512, 0, w * 128, acc);
#pragma unroll
        for (int mt = 0; mt < 2; ++mt)
#pragma unroll
            for (int j = 0; j < 8; ++j)
#pragma unroll
                for (int reg = 0; reg < 4; ++reg) {
                    int lrow = mt * 16 + lg * 4 + reg;
                    int col = w * 128 + j * 16 + r;
                    float v = acc[mt][j][reg] + ba[col];
                    v = isrelu ? fmaxf(v, 0.f) : tanh_(v);
                    u16 hv = f2bf(v);
                    int cc = col >> 3, sw = cc ^ (lrow & 7);
                    ldsB[(lrow * 64 + sw) * 8 + (col & 7)] = hv;
                    int row = rowg * 32 + lrow;
                    if (isrelu) st16(S2G + row * 512 + col, hv);
                    else        st32(HTFG + row * 512 + col, v);
                }
    }
    __syncthreads();
    {
        f32x4 acc[2][8] = {};
        gemm512<8>(ldsB, Wb, 512, 0, w * 128, acc);
#pragma unroll
        for (int mt = 0; mt < 2; ++mt)
#pragma unroll
            for (int j = 0; j < 8; ++j)
#pragma unroll
                for (int reg = 0; reg < 4; ++reg) {
                    int row = rowg * 32 + mt * 16 + lg * 4 + reg;
                    int col = w * 128 + j * 16 + r;
                    st32(OUT + row * 512 + col, acc[mt][j][reg] + bb[col]);
                }
    }
}

// P3: adaptive attention; thread-halves handle batch rows bid and bid+64.
struct AttSm { float whwL[512]; float hidL[2][512]; float zbuf[2][64]; float albuf[2][64]; };

__device__ __forceinline__ void p3_attn(int bid, const u16* __restrict__ VAB, const float* SEN,
                                        const float* HID, const float* __restrict__ whw,
                                        const float* __restrict__ whb, const u16* __restrict__ SPB,
                                        const u16* S2BF, const float* HTF, u16* CHHBF, AttSm* A) {
    int tid = threadIdx.x;
    int half = tid >> 7, th = tid & 127;
    int b = bid + half * 64;
    for (int i = tid; i < 512; i += 256) A->whwL[i] = whw[i];
    for (int i = th; i < 512; i += 128) A->hidL[half][i] = ld32(HID + (size_t)b * 512 + i);
    __syncthreads();
    int w2 = th >> 6, lane = tid & 63;
    for (int p = w2; p < 50; p += 2) {
        float part = 0.f;
        if (p < 49) {
            const u16* src = VAB + ((size_t)b * 49 + p) * 512;
#pragma unroll
            for (int it = 0; it < 8; ++it) {
                int a = lane + it * 64;
                part += tanh_(bf2f(src[a]) + A->hidL[half][a]) * A->whwL[a];
            }
        } else {
#pragma unroll
            for (int it = 0; it < 8; ++it) {
                int a = lane + it * 64;
                part += tanh_(ld32(SEN + (size_t)b * 512 + a) + A->hidL[half][a]) * A->whwL[a];
            }
        }
#pragma unroll
        for (int o = 32; o; o >>= 1) part += __shfl_xor(part, o, 64);
        if (lane == 0) A->zbuf[half][p] = part + whb[0];
    }
    __syncthreads();
    if (th < 64) {
        float v = (lane < 50) ? A->zbuf[half][lane] : -1e30f;
        float mx = v;
#pragma unroll
        for (int o = 32; o; o >>= 1) mx = fmaxf(mx, __shfl_xor(mx, o, 64));
        float e = (lane < 50) ? __expf(v - mx) : 0.f;
        float s = e;
#pragma unroll
        for (int o = 32; o; o >>= 1) s += __shfl_xor(s, o, 64);
        if (lane < 50) A->albuf[half][lane] = e / s;
    }
    __syncthreads();
    float a49 = A->albuf[half][49];
    int d0 = th * 4;
    unsigned s2a = ld32u(S2BF + (size_t)b * 512 + d0);
    unsigned s2b = ld32u(S2BF + (size_t)b * 512 + d0 + 2);
    float acc0 = a49 * bf2f((u16)s2a), acc1 = a49 * bf2f((u16)(s2a >> 16));
    float acc2 = a49 * bf2f((u16)s2b), acc3 = a49 * bf2f((u16)(s2b >> 16));
    for (int p = 0; p < 49; ++p) {
        const u16* sf = SPB + ((size_t)b * 49 + p) * 512 + d0;
        unsigned q0 = *(const unsigned*)sf, q1 = *(const unsigned*)(sf + 2);
        float al = A->albuf[half][p];
        acc0 += al * bf2f((u16)q0); acc1 += al * bf2f((u16)(q0 >> 16));
        acc2 += al * bf2f((u16)q1); acc3 += al * bf2f((u16)(q1 >> 16));
    }
    acc0 += ld32(HTF + (size_t)b * 512 + d0);
    acc1 += ld32(HTF + (size_t)b * 512 + d0 + 1);
    acc2 += ld32(HTF + (size_t)b * 512 + d0 + 2);
    acc3 += ld32(HTF + (size_t)b * 512 + d0 + 3);
    st32u(CHHBF + (size_t)b * 512 + d0, (unsigned)f2bf(acc0) | ((unsigned)f2bf(acc1) << 16));
    st32u(CHHBF + (size_t)b * 512 + d0 + 2, (unsigned)f2bf(acc2) | ((unsigned)f2bf(acc3) << 16));
}

// P4: chh -> att (full, redundant per rowg, ldsB) -> LSTM2 cell update.
// Unparks g2p partials (written by this block in P2 with identical lane map).
__device__ __forceinline__ void p4_lstm2(int bid, const u16* CHHBF,
                                         const u16* __restrict__ WPB, const float* __restrict__ wp_b,
                                         const u16* __restrict__ W2AS, const float* park,
                                         const float* __restrict__ b_ih2, const float* __restrict__ b_hh2,
                                         float* M2, u16* H2BF, u16* H2ALL, int t, u16* lds) {
    int rowg = bid >> 3, colg = bid & 7;
    int w = threadIdx.x >> 6, lane = threadIdx.x & 63, r = lane & 15, lg = lane >> 4;
    f32x4 acc2[2][4];
#pragma unroll
    for (int mt = 0; mt < 2; ++mt)
#pragma unroll
        for (int j = 0; j < 4; ++j)
#pragma unroll
            for (int reg = 0; reg < 4; ++reg)
                acc2[mt][j][reg] = park[(mt * 16 + j * 4 + reg) * 256 + threadIdx.x];
    u16* ldsB = lds + 16384;           // reuses park space; safe after stage512's entry sync
    stage512(lds, CHHBF, rowg * 32);
    {
        f32x4 acc1[2][8] = {};
        gemm512<8>(lds, WPB, 512, 0, w * 128, acc1);
#pragma unroll
        for (int mt = 0; mt < 2; ++mt)
#pragma unroll
            for (int j = 0; j < 8; ++j)
#pragma unroll
                for (int reg = 0; reg < 4; ++reg) {
                    int lrow = mt * 16 + lg * 4 + reg;
                    int col = w * 128 + j * 16 + r;
                    u16 hv = f2bf(tanh_(acc1[mt][j][reg] + wp_b[col]));
                    int cc = col >> 3, sw = cc ^ (lrow & 7);
                    ldsB[(lrow * 64 + sw) * 8 + (col & 7)] = hv;
                }
    }
    __syncthreads();
    gemm512<4>(ldsB, W2AS, 512, 0, colg * 256 + w * 64, acc2);
    int d = colg * 64 + w * 16 + r;
#pragma unroll
    for (int mt = 0; mt < 2; ++mt)
#pragma unroll
        for (int reg = 0; reg < 4; ++reg) {
            int lrow = mt * 16 + lg * 4 + reg;
            int row = rowg * 32 + lrow;
            float gi = acc2[mt][0][reg] + b_ih2[d]        + b_hh2[d];
            float gf = acc2[mt][1][reg] + b_ih2[512 + d]  + b_hh2[512 + d];
            float gg = acc2[mt][2][reg] + b_ih2[1024 + d] + b_hh2[1024 + d];
            float go = acc2[mt][3][reg] + b_ih2[1536 + d] + b_hh2[1536 + d];
            int pidx = bid * 2048 + lrow * 64 + (w * 16 + r);
            float m2n = sigm(gf) * M2[pidx] + sigm(gi) * tanh_(gg);
            M2[pidx] = m2n;
            u16 hb = f2bf(sigm(go) * tanh_(m2n));
            st16(H2BF + row * 512 + d, hb);
            st16(H2ALL + ((size_t)t * 128 + row) * 512 + d, hb);
        }
}

struct ScanSm {
    union {
        ull stage[4096];   // 32 KiB A-stage
        AttSm att;         // ~7 KiB attention arrays
    } u;
    float park[8192];      // 32 KiB g2p park (== lds+16384 u16, ldsB for chain/P4)
};

__global__ __launch_bounds__(256) void k_scan(
    const u16* __restrict__ W1HS, const u16* __restrict__ W2HS, const u16* __restrict__ W2AS,
    const u16* __restrict__ AFFS, const u16* __restrict__ AFFH,
    const u16* __restrict__ WSB, const u16* __restrict__ WGB, const u16* __restrict__ WPB,
    const float* __restrict__ P1, const float* __restrict__ PS,
    const u16* __restrict__ VAB, const u16* __restrict__ SPB,
    const float* __restrict__ b_ih2, const float* __restrict__ b_hh2,
    const float* __restrict__ affs_b, const float* __restrict__ affh_b,
    const float* __restrict__ wg_b, const float* __restrict__ ws_b, const float* __restrict__ wp_b,
    const float* __restrict__ whw, const float* __restrict__ whb,
    u16* H1A, u16* H1B, u16* H2BF, u16* STBF, u16* S2BF, u16* CHHBF,
    float* M1, float* M2, float* HTF, float* HID, float* SEN,
    u16* H2ALL, int* bar) {
    __shared__ ScanSm sm;
    u16* lds = (u16*)&sm;
    int bid = blockIdx.x;
    int bi = 0;
    for (int t = 0; t < 49; ++t) {
        const u16* h1c = (t & 1) ? H1B : H1A;
        u16* h1n = (t & 1) ? H1A : H1B;
        if (bid < 32) p1_lstm1(bid, H2BF, h1c, W1HS, P1, PS, M1, h1n, STBF, t, lds);
        grid_barrier(bar, bi++);
        if (bid < 32)      p2_g2p(bid, h1n, H2BF, W2HS, sm.park, lds);
        else if (bid < 36) p2_chain(bid - 32, STBF, AFFS, affs_b, true,  WSB, ws_b, S2BF, HTF, SEN, lds);
        else if (bid < 40) p2_chain(bid - 36, h1n, AFFH, affh_b, false, WGB, wg_b, S2BF, HTF, HID, lds);
        grid_barrier(bar, bi++);
        p3_attn(bid, VAB, SEN, HID, whw, whb, SPB, S2BF, HTF, CHHBF, &sm.u.att);
        grid_barrier(bar, bi++);
        if (bid < 32) p4_lstm2(bid, CHHBF, WPB, wp_b, W2AS, sm.park, b_ih2, b_hh2, M2, H2BF, H2ALL, t, lds);
        if (t < 48) grid_barrier(bar, bi++);
    }
}

// Final: preds[b][t][v] = H2all[t*128+b] @ fc_w^T + fc_b
__global__ __launch_bounds__(256) void k_fc(const u16* __restrict__ H2ALL, const u16* __restrict__ FCB,
                                            const float* __restrict__ fc_b, float* __restrict__ out) {
    int bid = blockIdx.x;
    int ng = bid % 157, mg = bid / 157;
    int w = threadIdx.x >> 6, lane = threadIdx.x & 63, r = lane & 15, lg = lane >> 4;
    int m_base = mg * 128 + w * 32;
    int n_base = ng * 64;
    int nt = (10000 - n_base) / 16; if (nt > 4) nt = 4;
    f32x4 acc[2][4] = {};
    gemm_2x4(H2ALL, H2ALL, 1 << 28, 512, 512, FCB, 512, 512, m_base, n_base, nt, acc);
#pragma unroll
    for (int mt = 0; mt < 2; ++mt)
#pragma unroll
        for (int j = 0; j < 4; ++j) {
            if (j < nt) {
#pragma unroll
                for (int reg = 0; reg < 4; ++reg) {
                    int row = m_base + mt * 16 + lg * 4 + reg;
                    int col = n_base + j * 16 + r;
                    int t = row >> 7, b = row & 127;
                    out[((size_t)b * 49 + t) * 10000 + col] = acc[mt][j][reg] + fc_b[col];
                }
            }
        }
}

// ---------------------------------------------------------------------------

extern "C" void kernel_launch(void* const* d_in, const int* in_sizes, int n_in,
                              void* d_out, int out_size, void* d_ws, size_t ws_size,
                              hipStream_t stream) {
    (void)in_sizes; (void)n_in; (void)out_size; (void)ws_size;

    const float* SF      = (const float*)d_in[0];
    const float* GIMG    = (const float*)d_in[1];
    const int*   CAP     = (const int*)d_in[2];
    const float* EMB     = (const float*)d_in[4];
    const float* w_ih1   = (const float*)d_in[5];
    const float* w_hh1   = (const float*)d_in[6];
    const float* b_ih1   = (const float*)d_in[7];
    const float* b_hh1   = (const float*)d_in[8];
    const float* s_wx    = (const float*)d_in[9];
    const float* s_bx    = (const float*)d_in[10];
    const float* s_wh    = (const float*)d_in[11];
    const float* s_bh    = (const float*)d_in[12];
    const float* w_ih2   = (const float*)d_in[13];
    const float* w_hh2   = (const float*)d_in[14];
    const float* b_ih2   = (const float*)d_in[15];
    const float* b_hh2   = (const float*)d_in[16];
    const float* aff_s_w = (const float*)d_in[17];
    const float* aff_s_b = (const float*)d_in[18];
    const float* aff_h_w = (const float*)d_in[19];
    const float* aff_h_b = (const float*)d_in[20];
    const float* ws_w    = (const float*)d_in[21];
    const float* ws_b    = (const float*)d_in[22];
    const float* wg_w    = (const float*)d_in[23];
    const float* wg_b    = (const float*)d_in[24];
    const float* wv_w    = (const float*)d_in[25];
    const float* wv_b    = (const float*)d_in[26];
    const float* wh_w    = (const float*)d_in[27];
    const float* wh_b    = (const float*)d_in[28];
    const float* wp_w    = (const float*)d_in[29];
    const float* wp_b    = (const float*)d_in[30];
    const float* fc_w    = (const float*)d_in[31];
    const float* fc_b    = (const float*)d_in[32];

    float* out = (float*)d_out;

    // fp32 scratch in d_out (fc overwrites all of d_out at the end):
    float* P1 = out;                       // 49*128*2048 = 12,845,056 floats
    float* PS = out + 12845056;            //  3,211,264 floats
    u16*  XWB = (u16*)(out + 17000000);    //  6,422,528 u16 (consumed before scan)

    char* ws = (char*)d_ws;
    size_t off = 0;
    auto alloc = [&](size_t elts, size_t esz) -> void* {
        void* p = ws + off;
        off += (elts * esz + 255) & ~(size_t)255;
        return p;
    };
    u16* W1HS  = (u16*)alloc(2621440, 2);
    u16* W2HS  = (u16*)alloc(2097152, 2);
    u16* W2AS  = (u16*)alloc(1048576, 2);
    u16* W1X   = (u16*)alloc(2097152, 2);
    u16* WSX   = (u16*)alloc(524288, 2);
    u16* AFFS  = (u16*)alloc(262144, 2);
    u16* AFFH  = (u16*)alloc(262144, 2);
    u16* WSB   = (u16*)alloc(262144, 2);
    u16* WGB   = (u16*)alloc(262144, 2);
    u16* WVB   = (u16*)alloc(262144, 2);
    u16* WPB   = (u16*)alloc(262144, 2);
    u16* FCB   = (u16*)alloc(5120000, 2);
    u16* SPB   = (u16*)alloc(3211264, 2);
    u16* VAB   = (u16*)alloc(3211264, 2);
    u16* H2ALL = (u16*)alloc(3211264, 2);
    u16* H1A   = (u16*)alloc(65536, 2);
    u16* H1B   = (u16*)alloc(65536, 2);
    u16* H2BF  = (u16*)alloc(65536, 2);
    u16* STBF  = (u16*)alloc(65536, 2);
    u16* S2BF  = (u16*)alloc(65536, 2);
    u16* CHHBF = (u16*)alloc(65536, 2);
    float* M1  = (float*)alloc(65536, 4);
    float* M2  = (float*)alloc(65536, 4);
    float* HTF = (float*)alloc(65536, 4);
    float* HID = (float*)alloc(65536, 4);
    float* SEN = (float*)alloc(65536, 4);
    int*   BAR = (int*)alloc(2048, 4);

    // zero-init recurrent state + barrier counters (every call / replay)
    hipMemsetAsync(H1A, 0, 65536 * 2, stream);
    hipMemsetAsync(H2BF, 0, 65536 * 2, stream);
    hipMemsetAsync(M1, 0, 65536 * 4, stream);
    hipMemsetAsync(M2, 0, 65536 * 4, stream);
    hipMemsetAsync(BAR, 0, 2048 * 4, stream);

    // prep: conversions + packs + xw gather
    k_cvt8<<<38688, 256, 0, stream>>>(aff_s_w, aff_h_w, ws_w, wg_w, wv_w, wp_w, fc_w, SF,
                                      AFFS, AFFH, WSB, WGB, WVB, WPB, FCB, SPB);
    k_packX<<<(2621440 + 255) / 256, 256, 0, stream>>>(w_ih1, s_wx, W1X, WSX);
    k_packS<<<(5767168 + 255) / 256, 256, 0, stream>>>(w_ih1, w_hh1, s_wx, s_wh, w_ih2, w_hh2,
                                                       W1HS, W2HS, W2AS);
    k_xw<<<(6422528 + 255) / 256, 256, 0, stream>>>(EMB, GIMG, CAP, XWB, 6422528);

    // batched precompute GEMMs
    k_p1ps<<<49 * 40, 256, 0, stream>>>(XWB, W1X, WSX, b_ih1, b_hh1, s_bx, s_bh, P1, PS);
    k_va<<<49 * 8, 256, 0, stream>>>(SPB, WVB, wv_b, VAB);

    // persistent sequential scan (64 co-resident blocks, fence-free barriers)
    k_scan<<<NBLK, 256, 0, stream>>>(W1HS, W2HS, W2AS, AFFS, AFFH, WSB, WGB, WPB,
                                     P1, PS, VAB, SPB, b_ih2, b_hh2, aff_s_b, aff_h_b,
                                     wg_b, ws_b, wp_b, wh_w, wh_b,
                                     H1A, H1B, H2BF, STBF, S2BF, CHHBF,
                                     M1, M2, HTF, HID, SEN, H2ALL, BAR);

    // final projection to vocab
    k_fc<<<49 * 157, 256, 0, stream>>>(H2ALL, FCB, fc_b, out);
}